// Round 3
// baseline (9238.565 us; speedup 1.0000x reference)
//
#include <hip/hip_runtime.h>

typedef unsigned short u16;
typedef unsigned int   u32;
typedef __attribute__((ext_vector_type(8))) short bfx8;
typedef __attribute__((ext_vector_type(4))) float f32x4;

#define NN 131072      // nodes
#define NE 1500000     // edges
#define HH 128         // hidden
#define NG 12          // col groups: [sp_root, tp_root, W_0..W_9]

__device__ __forceinline__ u16 f2b(float f) {
  u32 u = __float_as_uint(f);
  u32 r = (u + 0x7FFFu + ((u >> 16) & 1u)) >> 16;
  return (u16)r;
}
__device__ __forceinline__ float b2f(u32 lo16) {
  return __uint_as_float(lo16 << 16);
}

// ---------------- per-(rel,dst) counts + per-dst degree (once per call) ------
__global__ __launch_bounds__(256) void k_count2(const int* __restrict__ et,
                                                const int* __restrict__ dst,
                                                int* __restrict__ cnt,
                                                int* __restrict__ deg) {
  int e = blockIdx.x * 256 + threadIdx.x;
  if (e >= NE) return;
  int r = et[e];
  if (r < 0 || r >= 10) return;
  int d = dst[e];
  atomicAdd(&cnt[(size_t)r * NN + d], 1);
  atomicAdd(&deg[d], 1);
}

__global__ __launch_bounds__(256) void k_inv(int* __restrict__ cnt) {
  int i = blockIdx.x * 256 + threadIdx.x;
  if (i >= 10 * NN) return;
  int c = cnt[i]; if (c < 1) c = 1;
  ((float*)cnt)[i] = 1.0f / (float)c;   // in-place int -> float reciprocal
}

// ---------------- exclusive scan of deg -> rowptr, cursor (single block) -----
__global__ __launch_bounds__(1024) void k_scan(const int* __restrict__ deg,
                                               int* __restrict__ rowptr,
                                               int* __restrict__ cursor) {
  __shared__ int part[1024];
  int t = threadIdx.x;
  int base = t * 128;
  int s = 0;
  for (int i = 0; i < 128; ++i) s += deg[base + i];
  part[t] = s;
  __syncthreads();
  for (int off = 1; off < 1024; off <<= 1) {
    int u = (t >= off) ? part[t - off] : 0;
    __syncthreads();
    part[t] += u;
    __syncthreads();
  }
  int run = part[t] - s;   // exclusive prefix
  for (int i = 0; i < 128; ++i) {
    int dv = deg[base + i];
    rowptr[base + i] = run;
    cursor[base + i] = run;
    run += dv;
  }
  if (t == 1023) rowptr[NN] = run;
}

// ---------------- CSR fill: colidx[pos] = (src<<4)|rel -----------------------
__global__ __launch_bounds__(256) void k_fill(const int* __restrict__ src,
                                              const int* __restrict__ dst,
                                              const int* __restrict__ et,
                                              int* __restrict__ cursor,
                                              u32* __restrict__ colidx) {
  int e = blockIdx.x * 256 + threadIdx.x;
  if (e >= NE) return;
  int r = et[e];
  if (r < 0 || r >= 10) return;
  int d = dst[e];
  int pos = atomicAdd(&cursor[d], 1);
  colidx[pos] = ((u32)src[e] << 4) | (u32)r;
}

// ---------------- build W^T (bf16): Wall[g][j][k] = W_g[k][j] ----------------
__global__ __launch_bounds__(256) void k_buildw(
    const float* __restrict__ sp_root, const float* __restrict__ tp_root,
    const float* __restrict__ sp_basis, const float* __restrict__ sp_comp,
    const float* __restrict__ tp_basis, const float* __restrict__ tp_comp,
    u16* __restrict__ W) {
  int g = blockIdx.y;
  int idx = blockIdx.x * 256 + threadIdx.x;   // 0..16383
  int j = idx >> 7, k = idx & 127;
  float v = 0.f;
  if (g == 0) v = sp_root[k * 128 + j];
  else if (g == 1) v = tp_root[k * 128 + j];
  else if (g < 9) {
    int r = g - 2;
#pragma unroll
    for (int b = 0; b < 4; ++b) v += sp_comp[r * 4 + b] * sp_basis[b * 16384 + k * 128 + j];
  } else {
    int r = g - 9;
#pragma unroll
    for (int b = 0; b < 3; ++b) v += tp_comp[r * 3 + b] * tp_basis[b * 16384 + k * 128 + j];
  }
  W[(size_t)g * 16384 + j * 128 + k] = f2b(v);
}

// ---------------- MFMA GEMM: C[g][M][128] = A[M][128] @ W_g, bf16 ------------
__global__ __launch_bounds__(256) void k_gemm(const u16* __restrict__ A,
                                              const u16* __restrict__ Bt,
                                              u16* __restrict__ C) {
  __shared__ u16 As[128][136];
  __shared__ u16 Bs[128][136];
  int t = threadIdx.x;
  const u16* Ab = A + (size_t)blockIdx.x * 128 * 128;
  const u16* Bb = Bt + (size_t)blockIdx.y * 128 * 128;
  {
    int row = t >> 4;
    int ko = (t & 15) * 8;
#pragma unroll
    for (int it = 0; it < 8; ++it) {
      int r = row + it * 16;
      *(bfx8*)&As[r][ko] = *(const bfx8*)&Ab[r * 128 + ko];
      *(bfx8*)&Bs[r][ko] = *(const bfx8*)&Bb[r * 128 + ko];
    }
  }
  __syncthreads();
  int wid = t >> 6, lane = t & 63;
  int wm = (wid & 1) * 64, wn = (wid >> 1) * 64;
  int lr = lane & 15, lk = (lane >> 4) * 8;
  f32x4 acc[4][4] = {};
#pragma unroll
  for (int kk = 0; kk < 4; ++kk) {
    int k = kk * 32 + lk;
    bfx8 a[4], b[4];
#pragma unroll
    for (int m = 0; m < 4; ++m) a[m] = *(const bfx8*)&As[wm + m * 16 + lr][k];
#pragma unroll
    for (int n = 0; n < 4; ++n) b[n] = *(const bfx8*)&Bs[wn + n * 16 + lr][k];
#pragma unroll
    for (int m = 0; m < 4; ++m)
#pragma unroll
      for (int n = 0; n < 4; ++n)
        acc[m][n] = __builtin_amdgcn_mfma_f32_16x16x32_bf16(a[m], b[n], acc[m][n], 0, 0, 0);
  }
  u16* Cb = C + (size_t)blockIdx.y * NN * HH + (size_t)blockIdx.x * 128 * 128;
  int rbase = (lane >> 4) * 4;
#pragma unroll
  for (int m = 0; m < 4; ++m)
#pragma unroll
    for (int n = 0; n < 4; ++n)
#pragma unroll
      for (int v = 0; v < 4; ++v) {
        int row = wm + m * 16 + rbase + v;
        int col = wn + n * 16 + lr;
        Cb[row * 128 + col] = f2b(acc[m][n][v]);
      }
}

// ---------------- fused gather + root + fuse matvec + LN + residual ----------
// 512 thr (8 waves). Half-wave (32 lanes) per dst; wave covers 2 dsts/iter.
__global__ __launch_bounds__(512) void k_aggfuse(
    const u16* __restrict__ Table, const int* __restrict__ rowptr,
    const u32* __restrict__ colidx, const float* __restrict__ inv,
    const float* __restrict__ fw, const float* __restrict__ fb,
    const float* __restrict__ lng, const float* __restrict__ lnb,
    const float* __restrict__ spb, const float* __restrict__ tpb,
    u16* __restrict__ hb, int first) {
  __shared__ u16 Wf[256 * 128];          // 64 KiB bf16 fuse weights
  __shared__ float cat[8][2][256];       // 16 KiB, per-wave private
  for (int i = threadIdx.x * 4; i < 256 * 128; i += 2048) {
    f32x4 v = *(const f32x4*)&fw[i];
    uint2 pk;
    pk.x = (u32)f2b(v.x) | ((u32)f2b(v.y) << 16);
    pk.y = (u32)f2b(v.z) | ((u32)f2b(v.w) << 16);
    *(uint2*)&Wf[i] = pk;
  }
  int w = threadIdx.x >> 6, lane = threadIdx.x & 63;
  int h = lane >> 5, sub = lane & 31;
  int o0 = 2 * lane, o1 = o0 + 1;
  f32x4 sb = *(const f32x4*)&spb[sub * 4];
  f32x4 tb = *(const f32x4*)&tpb[sub * 4];
  float fb0 = fb[o0], fb1 = fb[o1];
  float g0v = lng[o0], g1v = lng[o1], b0v = lnb[o0], b1v = lnb[o1];
  __syncthreads();
  int gw = blockIdx.x * 8 + w;           // 0..4095
  for (int it = 0; it < 16; ++it) {
    int dpair = it * 4096 + gw;          // 0..65535
    int d = dpair * 2 + h;
    int beg = rowptr[d], end = rowptr[d + 1];
    float s0 = 0, s1 = 0, s2 = 0, s3 = 0, t0 = 0, t1 = 0, t2 = 0, t3 = 0;
    u32 ci = (beg < end) ? colidx[beg] : 0;
    for (int i = beg; i < end; ++i) {
      u32 cc = ci;
      if (i + 1 < end) ci = colidx[i + 1];   // prefetch next entry
      int r = (int)(cc & 15u);
      int sn = (int)(cc >> 4);
      float sc = inv[r * NN + d];
      uint2 v = *(const uint2*)&Table[((size_t)(r + 2) * NN + sn) * HH + sub * 4];
      float a0 = b2f(v.x & 0xFFFFu), a1 = b2f(v.x >> 16);
      float a2 = b2f(v.y & 0xFFFFu), a3 = b2f(v.y >> 16);
      if (r < 7) {
        s0 = fmaf(sc, a0, s0); s1 = fmaf(sc, a1, s1);
        s2 = fmaf(sc, a2, s2); s3 = fmaf(sc, a3, s3);
      } else {
        t0 = fmaf(sc, a0, t0); t1 = fmaf(sc, a1, t1);
        t2 = fmaf(sc, a2, t2); t3 = fmaf(sc, a3, t3);
      }
    }
    {
      uint2 v = *(const uint2*)&Table[((size_t)d) * HH + sub * 4];            // sp_root
      s0 += b2f(v.x & 0xFFFFu) + sb.x; s1 += b2f(v.x >> 16) + sb.y;
      s2 += b2f(v.y & 0xFFFFu) + sb.z; s3 += b2f(v.y >> 16) + sb.w;
    }
    {
      uint2 v = *(const uint2*)&Table[((size_t)NN + d) * HH + sub * 4];       // tp_root
      t0 += b2f(v.x & 0xFFFFu) + tb.x; t1 += b2f(v.x >> 16) + tb.y;
      t2 += b2f(v.y & 0xFFFFu) + tb.z; t3 += b2f(v.y >> 16) + tb.w;
    }
    *(f32x4*)&cat[w][h][sub * 4]       = (f32x4){s0, s1, s2, s3};
    *(f32x4*)&cat[w][h][128 + sub * 4] = (f32x4){t0, t1, t2, t3};
    __syncthreads();   // uniform trips across all waves; orders LDS write->read
    float a00 = 0, a01 = 0, a10 = 0, a11 = 0;
#pragma unroll 8
    for (int f = 0; f < 256; ++f) {
      u32 wv = *(const u32*)&Wf[f * 128 + o0];
      float wx = b2f(wv & 0xFFFFu), wy = b2f(wv >> 16);
      float c0 = cat[w][0][f], c1 = cat[w][1][f];
      a00 = fmaf(c0, wx, a00); a01 = fmaf(c0, wy, a01);
      a10 = fmaf(c1, wx, a10); a11 = fmaf(c1, wy, a11);
    }
#pragma unroll
    for (int half = 0; half < 2; ++half) {
      int dn = dpair * 2 + half;
      float v0 = (half ? a10 : a00) + fb0;
      float v1 = (half ? a11 : a01) + fb1;
      float s = v0 + v1;
#pragma unroll
      for (int dx = 1; dx < 64; dx <<= 1) s += __shfl_xor(s, dx);
      float mu = s * (1.f / 128.f);
      float e0 = v0 - mu, e1 = v1 - mu;
      float q = e0 * e0 + e1 * e1;
#pragma unroll
      for (int dx = 1; dx < 64; dx <<= 1) q += __shfl_xor(q, dx);
      float rstd = rsqrtf(q * (1.f / 128.f) + 1e-5f);
      float y0 = fmaxf(e0 * rstd * g0v + b0v, 0.f);
      float y1 = fmaxf(e1 * rstd * g1v + b1v, 0.f);
      size_t pp = (size_t)dn * HH;
      if (!first) {
        u32 hv = *(const u32*)&hb[pp + o0];
        y0 += b2f(hv & 0xFFFFu);
        y1 += b2f(hv >> 16);
      }
      *(u32*)&hb[pp + o0] = (u32)f2b(y0) | ((u32)f2b(y1) << 16);
    }
  }
}

// ---------------- fallback-path kernels (chunked atomic scatter) -------------
__global__ __launch_bounds__(256) void k_init1(const u16* __restrict__ T,
                                               const float* __restrict__ bias,
                                               float* __restrict__ dst) {
  size_t i4 = ((size_t)blockIdx.x * 256 + threadIdx.x) * 4;
  if (i4 >= (size_t)NN * HH) return;
  int j = (int)(i4 & 127);
  uint2 a = *(const uint2*)&T[i4];
  dst[i4 + 0] = b2f(a.x & 0xFFFFu) + bias[j + 0];
  dst[i4 + 1] = b2f(a.x >> 16)     + bias[j + 1];
  dst[i4 + 2] = b2f(a.y & 0xFFFFu) + bias[j + 2];
  dst[i4 + 3] = b2f(a.y >> 16)     + bias[j + 3];
}

__global__ __launch_bounds__(256) void k_scatter(
    const u16* __restrict__ Table, const int* __restrict__ src,
    const int* __restrict__ dst, const int* __restrict__ et,
    const float* __restrict__ inv, float* __restrict__ hs,
    float* __restrict__ ht, int g0, int rlo, int rhi) {
  u32 tid = blockIdx.x * 256 + threadIdx.x;
  u32 e = tid >> 5;
  if (e >= NE) return;
  int r = et[e];
  if (r < rlo || r >= rhi) return;
  int sub = tid & 31;
  int s = src[e], d = dst[e];
  float sc = inv[(size_t)r * NN + d];
  const u16* row = Table + ((size_t)(r + 2 - g0) * NN + s) * HH + sub * 4;
  float* o = (r < 7 ? hs : ht) + (size_t)d * HH + sub * 4;
  uint2 v = *(const uint2*)row;
  unsafeAtomicAdd(o + 0, sc * b2f(v.x & 0xFFFFu));
  unsafeAtomicAdd(o + 1, sc * b2f(v.x >> 16));
  unsafeAtomicAdd(o + 2, sc * b2f(v.y & 0xFFFFu));
  unsafeAtomicAdd(o + 3, sc * b2f(v.y >> 16));
}

__global__ __launch_bounds__(256) void k_fuse(
    const float* __restrict__ hs, const float* __restrict__ ht,
    const float* __restrict__ fw, const float* __restrict__ fb,
    const float* __restrict__ lng, const float* __restrict__ lnb,
    u16* __restrict__ hb, int first) {
  __shared__ u16 Wf[256 * 128];
  __shared__ float cat[4][4][256];
  for (int i = threadIdx.x * 4; i < 256 * 128; i += 1024) {
    f32x4 v = *(const f32x4*)&fw[i];
    uint2 pk;
    pk.x = (u32)f2b(v.x) | ((u32)f2b(v.y) << 16);
    pk.y = (u32)f2b(v.z) | ((u32)f2b(v.w) << 16);
    *(uint2*)&Wf[i] = pk;
  }
  __syncthreads();
  int wid = threadIdx.x >> 6, lane = threadIdx.x & 63;
  int o0 = 2 * lane, o1 = o0 + 1;
  float fb0 = fb[o0], fb1 = fb[o1];
  float g0v = lng[o0], g1v = lng[o1], b0v = lnb[o0], b1v = lnb[o1];
  for (int base = blockIdx.x * 16; base < NN; base += gridDim.x * 16) {
    int n0 = base + wid * 4;
#pragma unroll
    for (int nd = 0; nd < 4; ++nd) {
      size_t pp = (size_t)(n0 + nd) * HH;
      cat[wid][nd][lane]       = hs[pp + lane];
      cat[wid][nd][lane + 64]  = hs[pp + lane + 64];
      cat[wid][nd][lane + 128] = ht[pp + lane];
      cat[wid][nd][lane + 192] = ht[pp + lane + 64];
    }
    float acc[4][2] = {};
    for (int f = 0; f < 256; ++f) {
      u32 w = *(const u32*)&Wf[f * 128 + o0];
      float wx = b2f(w & 0xFFFFu), wy = b2f(w >> 16);
#pragma unroll
      for (int nd = 0; nd < 4; ++nd) {
        float c = cat[wid][nd][f];
        acc[nd][0] = fmaf(c, wx, acc[nd][0]);
        acc[nd][1] = fmaf(c, wy, acc[nd][1]);
      }
    }
#pragma unroll
    for (int nd = 0; nd < 4; ++nd) {
      int n = n0 + nd;
      float v0 = acc[nd][0] + fb0, v1 = acc[nd][1] + fb1;
      float s = v0 + v1;
#pragma unroll
      for (int dx = 1; dx < 64; dx <<= 1) s += __shfl_xor(s, dx);
      float mu = s * (1.f / 128.f);
      float d0 = v0 - mu, d1 = v1 - mu;
      float q = d0 * d0 + d1 * d1;
#pragma unroll
      for (int dx = 1; dx < 64; dx <<= 1) q += __shfl_xor(q, dx);
      float rstd = rsqrtf(q * (1.f / 128.f) + 1e-5f);
      float y0 = fmaxf(d0 * rstd * g0v + b0v, 0.f);
      float y1 = fmaxf(d1 * rstd * g1v + b1v, 0.f);
      size_t pp = (size_t)n * HH;
      if (!first) {
        u32 hv = *(const u32*)&hb[pp + o0];
        y0 += b2f(hv & 0xFFFFu);
        y1 += b2f(hv >> 16);
      }
      *(u32*)&hb[pp + o0] = (u32)f2b(y0) | ((u32)f2b(y1) << 16);
    }
  }
}

// ---------------- input projection: h = x @ w_in + b_in (bf16 out) -----------
__global__ __launch_bounds__(256) void k_input(const float* __restrict__ x,
                                               const float* __restrict__ w,
                                               const float* __restrict__ bias,
                                               u16* __restrict__ hb) {
  __shared__ float Ws[64 * 128];
  __shared__ float xr[4][4][64];
  for (int i = threadIdx.x * 4; i < 64 * 128; i += 1024)
    *(f32x4*)&Ws[i] = *(const f32x4*)&w[i];
  __syncthreads();
  int wid = threadIdx.x >> 6, lane = threadIdx.x & 63;
  int o0 = 2 * lane, o1 = o0 + 1;
  float b0 = bias[o0], b1 = bias[o1];
  for (int base = blockIdx.x * 16; base < NN; base += gridDim.x * 16) {
    int n0 = base + wid * 4;
#pragma unroll
    for (int nd = 0; nd < 4; ++nd)
      xr[wid][nd][lane] = x[(size_t)(n0 + nd) * 64 + lane];
    float acc[4][2] = {};
    for (int f = 0; f < 64; ++f) {
      float2 wv = *(const float2*)&Ws[f * 128 + o0];
#pragma unroll
      for (int nd = 0; nd < 4; ++nd) {
        float c = xr[wid][nd][f];
        acc[nd][0] = fmaf(c, wv.x, acc[nd][0]);
        acc[nd][1] = fmaf(c, wv.y, acc[nd][1]);
      }
    }
#pragma unroll
    for (int nd = 0; nd < 4; ++nd) {
      size_t pp = (size_t)(n0 + nd) * HH;
      float y0 = acc[nd][0] + b0, y1 = acc[nd][1] + b1;
      *(u32*)&hb[pp + o0] = (u32)f2b(y0) | ((u32)f2b(y1) << 16);
    }
  }
}

// ---------------- head: out = relu(h@W1+b1)@W2 + b2 --------------------------
__global__ __launch_bounds__(256) void k_head(const u16* __restrict__ hbuf,
                                              const float* __restrict__ w1,
                                              const float* __restrict__ b1,
                                              const float* __restrict__ w2,
                                              const float* __restrict__ b2,
                                              float* __restrict__ out) {
  __shared__ u16 W1s[128 * 128];
  __shared__ u16 W2s[128 * 32];
  __shared__ float hr[4][4][128];
  __shared__ float h1[4][4][128];
  for (int i = threadIdx.x * 4; i < 128 * 128; i += 1024) {
    f32x4 v = *(const f32x4*)&w1[i];
    uint2 pk;
    pk.x = (u32)f2b(v.x) | ((u32)f2b(v.y) << 16);
    pk.y = (u32)f2b(v.z) | ((u32)f2b(v.w) << 16);
    *(uint2*)&W1s[i] = pk;
  }
  for (int i = threadIdx.x * 4; i < 128 * 32; i += 1024) {
    f32x4 v = *(const f32x4*)&w2[i];
    uint2 pk;
    pk.x = (u32)f2b(v.x) | ((u32)f2b(v.y) << 16);
    pk.y = (u32)f2b(v.z) | ((u32)f2b(v.w) << 16);
    *(uint2*)&W2s[i] = pk;
  }
  __syncthreads();
  int wid = threadIdx.x >> 6, lane = threadIdx.x & 63;
  int o0 = 2 * lane, o1 = o0 + 1;
  float bb0 = b1[o0], bb1 = b1[o1];
  int o2 = lane & 31, half = lane >> 5;
  float b2v = b2[o2];
  for (int base = blockIdx.x * 16; base < NN; base += gridDim.x * 16) {
    int n0 = base + wid * 4;
#pragma unroll
    for (int nd = 0; nd < 4; ++nd) {
      size_t pp = (size_t)(n0 + nd) * HH;
      u32 hv = *(const u32*)&hbuf[pp + o0];
      hr[wid][nd][o0] = b2f(hv & 0xFFFFu);
      hr[wid][nd][o1] = b2f(hv >> 16);
    }
    float acc[4][2] = {};
    for (int f = 0; f < 128; ++f) {
      u32 w = *(const u32*)&W1s[f * 128 + o0];
      float wx = b2f(w & 0xFFFFu), wy = b2f(w >> 16);
#pragma unroll
      for (int nd = 0; nd < 4; ++nd) {
        float c = hr[wid][nd][f];
        acc[nd][0] = fmaf(c, wx, acc[nd][0]);
        acc[nd][1] = fmaf(c, wy, acc[nd][1]);
      }
    }
#pragma unroll
    for (int nd = 0; nd < 4; ++nd) {
      h1[wid][nd][o0] = fmaxf(acc[nd][0] + bb0, 0.f);
      h1[wid][nd][o1] = fmaxf(acc[nd][1] + bb1, 0.f);
    }
#pragma unroll
    for (int nd2 = 0; nd2 < 2; ++nd2) {
      int nd = half * 2 + nd2;
      float a = 0.f;
      for (int f = 0; f < 128; ++f)
        a = fmaf(h1[wid][nd][f], b2f(W2s[f * 32 + o2]), a);
      out[(size_t)(n0 + nd) * 32 + o2] = a + b2v;
    }
  }
}

extern "C" void kernel_launch(void* const* d_in, const int* in_sizes, int n_in,
                              void* d_out, int out_size, void* d_ws, size_t ws_size,
                              hipStream_t stream) {
  const float* x        = (const float*)d_in[0];
  const int*   ei       = (const int*)d_in[1];
  const int*   et       = (const int*)d_in[2];
  const float* w_in     = (const float*)d_in[3];
  const float* b_in     = (const float*)d_in[4];
  const float* sp_basis = (const float*)d_in[5];
  const float* sp_comp  = (const float*)d_in[6];
  const float* sp_root  = (const float*)d_in[7];
  const float* sp_bias  = (const float*)d_in[8];
  const float* tp_basis = (const float*)d_in[9];
  const float* tp_comp  = (const float*)d_in[10];
  const float* tp_root  = (const float*)d_in[11];
  const float* tp_bias  = (const float*)d_in[12];
  const float* fuse_w   = (const float*)d_in[13];
  const float* fuse_b   = (const float*)d_in[14];
  const float* ln_g     = (const float*)d_in[15];
  const float* ln_b     = (const float*)d_in[16];
  const float* hw1      = (const float*)d_in[17];
  const float* hb1      = (const float*)d_in[18];
  const float* hw2      = (const float*)d_in[19];
  const float* hb2      = (const float*)d_in[20];

  char* p = (char*)d_ws;
  size_t off = 0;
  auto carve = [&](size_t bytes) {
    void* q = p + off;
    off += (bytes + 255) & ~(size_t)255;
    return q;
  };

  // ---- primary layout: CSR pull-gather, full 12-group Table -----------------
  u16* hb     = (u16*)carve((size_t)NN * HH * 2);        // 32 MiB
  int* cnt    = (int*)carve((size_t)10 * NN * 4);        //  5 MiB
  int* deg    = (int*)carve((size_t)NN * 4);
  int* rowptr = (int*)carve((size_t)(NN + 1) * 4);
  int* cursor = (int*)carve((size_t)NN * 4);
  u32* colidx = (u32*)carve((size_t)NE * 4);             //  6 MiB
  u16* Wall   = (u16*)carve((size_t)NG * 16384 * 2);
  u16* Table  = (u16*)carve((size_t)NG * NN * HH * 2);   // 384 MiB

  if (off <= ws_size) {
    hipMemsetAsync(cnt, 0, (size_t)10 * NN * 4, stream);
    hipMemsetAsync(deg, 0, (size_t)NN * 4, stream);
    k_count2<<<(NE + 255) / 256, 256, 0, stream>>>(et, ei + NE, cnt, deg);
    k_inv<<<(10 * NN + 255) / 256, 256, 0, stream>>>(cnt);
    k_scan<<<1, 1024, 0, stream>>>(deg, rowptr, cursor);
    k_fill<<<(NE + 255) / 256, 256, 0, stream>>>(ei, ei + NE, et, cursor, colidx);
    k_input<<<2048, 256, 0, stream>>>(x, w_in, b_in, hb);
    for (int l = 0; l < 3; ++l) {
      k_buildw<<<dim3(64, NG), 256, 0, stream>>>(
          sp_root + (size_t)l * 16384, tp_root + (size_t)l * 16384,
          sp_basis + (size_t)l * 4 * 16384, sp_comp + (size_t)l * 28,
          tp_basis + (size_t)l * 3 * 16384, tp_comp + (size_t)l * 9, Wall);
      k_gemm<<<dim3(NN / 128, NG), 256, 0, stream>>>(hb, Wall, Table);
      k_aggfuse<<<512, 512, 0, stream>>>(
          Table, rowptr, colidx, (const float*)cnt,
          fuse_w + (size_t)l * 32768, fuse_b + l * 128,
          ln_g + l * 128, ln_b + l * 128,
          sp_bias + l * 128, tp_bias + l * 128, hb, l == 0);
    }
    k_head<<<2048, 256, 0, stream>>>(hb, hw1, hb1, hw2, hb2, (float*)d_out);
    return;
  }

  // ---- fallback layout: chunked atomic-scatter path (proven in round 2) -----
  off = 0;
  float* hsb  = (float*)carve((size_t)NN * HH * 4);
  float* htb  = (float*)carve((size_t)NN * HH * 4);
  hb   = (u16*)carve((size_t)NN * HH * 2);
  cnt  = (int*)carve((size_t)10 * NN * 4);
  Wall = (u16*)carve((size_t)NG * 16384 * 2);
  size_t tbytes = (size_t)NN * HH * 2;
  long long avail = (long long)ws_size - (long long)off;
  int CC = (int)(avail > 0 ? avail / (long long)tbytes : 0);
  if (CC > NG) CC = NG;
  if (CC < 1) CC = 1;
  Table = (u16*)carve((size_t)CC * tbytes);

  hipMemsetAsync(cnt, 0, (size_t)10 * NN * 4, stream);
  k_count2<<<(NE + 255) / 256, 256, 0, stream>>>(et, ei + NE, cnt, (int*)hsb);  // deg unused; dummy
  hipMemsetAsync(hsb, 0, (size_t)NN * 4, stream);  // wipe dummy writes before use
  k_inv<<<(10 * NN + 255) / 256, 256, 0, stream>>>(cnt);
  k_input<<<2048, 256, 0, stream>>>(x, w_in, b_in, hb);

  const int initGrid = (int)(((size_t)NN * HH / 4 + 255) / 256);
  for (int l = 0; l < 3; ++l) {
    k_buildw<<<dim3(64, NG), 256, 0, stream>>>(
        sp_root + (size_t)l * 16384, tp_root + (size_t)l * 16384,
        sp_basis + (size_t)l * 4 * 16384, sp_comp + (size_t)l * 28,
        tp_basis + (size_t)l * 3 * 16384, tp_comp + (size_t)l * 9, Wall);
    for (int g0 = 0; g0 < NG; g0 += CC) {
      int ng = (NG - g0 < CC) ? NG - g0 : CC;
      k_gemm<<<dim3(NN / 128, ng), 256, 0, stream>>>(hb, Wall + (size_t)g0 * 16384, Table);
      if (g0 == 0)
        k_init1<<<initGrid, 256, 0, stream>>>(Table, sp_bias + l * 128, hsb);
      if (g0 <= 1 && g0 + ng > 1)
        k_init1<<<initGrid, 256, 0, stream>>>(Table + (size_t)(1 - g0) * NN * HH,
                                              tp_bias + l * 128, htb);
      int rlo = (g0 > 2 ? g0 - 2 : 0);
      int rhi = g0 + ng - 2;
      if (rhi > rlo)
        k_scatter<<<(NE * 32) / 256, 256, 0, stream>>>(
            Table, ei, ei + NE, et, (const float*)cnt, hsb, htb, g0, rlo, rhi);
    }
    k_fuse<<<2048, 256, 0, stream>>>(hsb, htb, fuse_w + (size_t)l * 32768,
                                     fuse_b + l * 128, ln_g + l * 128,
                                     ln_b + l * 128, hb, l == 0);
  }
  k_head<<<2048, 256, 0, stream>>>(hb, hw1, hb1, hw2, hb2, (float*)d_out);
}

// Round 4
// 2193.662 us; speedup vs baseline: 4.2115x; 4.2115x over previous
//
#include <hip/hip_runtime.h>

typedef unsigned short u16;
typedef unsigned int   u32;
typedef __attribute__((ext_vector_type(8))) short bfx8;
typedef __attribute__((ext_vector_type(4))) float f32x4;

#define NN 131072      // nodes
#define NE 1500000     // edges
#define HH 128         // hidden

__device__ __forceinline__ u16 f2b(float f) {
  u32 u = __float_as_uint(f);
  u32 r = (u + 0x7FFFu + ((u >> 16) & 1u)) >> 16;
  return (u16)r;
}
__device__ __forceinline__ float b2f(u32 lo16) {
  return __uint_as_float(lo16 << 16);
}

// ---------------- per-(rel,dst) counts + per-dst degree ----------------------
__global__ __launch_bounds__(256) void k_count2(const int* __restrict__ et,
                                                const int* __restrict__ dst,
                                                int* __restrict__ cnt,
                                                int* __restrict__ deg) {
  int e = blockIdx.x * 256 + threadIdx.x;
  if (e >= NE) return;
  int r = et[e];
  if (r < 0 || r >= 10) return;
  int d = dst[e];
  atomicAdd(&cnt[(size_t)r * NN + d], 1);
  atomicAdd(&deg[d], 1);
}

__global__ __launch_bounds__(256) void k_inv(int* __restrict__ cnt) {
  int i = blockIdx.x * 256 + threadIdx.x;
  if (i >= 10 * NN) return;
  int c = cnt[i]; if (c < 1) c = 1;
  ((float*)cnt)[i] = 1.0f / (float)c;   // in-place int -> float reciprocal
}

// ---------------- exclusive scan of deg -> rowptr (single block) -------------
__global__ __launch_bounds__(1024) void k_scan(const int* __restrict__ deg,
                                               int* __restrict__ rowptr) {
  __shared__ int part[1024];
  int t = threadIdx.x;
  int base = t * 128;
  int s = 0;
  for (int i = 0; i < 128; ++i) s += deg[base + i];
  part[t] = s;
  __syncthreads();
  for (int off = 1; off < 1024; off <<= 1) {
    int u = (t >= off) ? part[t - off] : 0;
    __syncthreads();
    part[t] += u;
    __syncthreads();
  }
  int run = part[t] - s;   // exclusive prefix
  for (int i = 0; i < 128; ++i) {
    rowptr[base + i] = run;
    run += deg[base + i];
  }
  if (t == 1023) rowptr[NN] = run;
}

// ---------------- per-(dst,rel) cursors from cnt + rowptr --------------------
__global__ __launch_bounds__(256) void k_rpd(const int* __restrict__ cnt,
                                             const int* __restrict__ rowptr,
                                             int* __restrict__ cursor) {
  int d = blockIdx.x * 256 + threadIdx.x;
  if (d >= NN) return;
  int run = rowptr[d];
#pragma unroll
  for (int r = 0; r < 10; ++r) {
    cursor[d * 10 + r] = run;
    run += cnt[(size_t)r * NN + d];
  }
}

// ---------------- CSR fill rel-sorted: colidx[pos] = (src<<4)|rel ------------
__global__ __launch_bounds__(256) void k_fill(const int* __restrict__ src,
                                              const int* __restrict__ dst,
                                              const int* __restrict__ et,
                                              int* __restrict__ cursor,
                                              u32* __restrict__ colidx) {
  int e = blockIdx.x * 256 + threadIdx.x;
  if (e >= NE) return;
  int r = et[e];
  if (r < 0 || r >= 10) return;
  int d = dst[e];
  int pos = atomicAdd(&cursor[d * 10 + r], 1);
  colidx[pos] = ((u32)src[e] << 4) | (u32)r;
}

// ---------------- per-layer weight prep (transposed bf16) --------------------
// WT[12][128][128]: g=0 sp_root^T, g=1..7 spW_r^T, g=8 tp_root^T, g=9..11 tpW^T
// FT[128][256]: fuse_w^T
__global__ __launch_bounds__(256) void k_prep(
    const float* __restrict__ sp_root, const float* __restrict__ tp_root,
    const float* __restrict__ sp_basis, const float* __restrict__ sp_comp,
    const float* __restrict__ tp_basis, const float* __restrict__ tp_comp,
    const float* __restrict__ fw, u16* __restrict__ WT, u16* __restrict__ FT) {
  int idx = blockIdx.x * 256 + threadIdx.x;
  if (idx < 196608) {
    int g = idx >> 14, rem = idx & 16383;
    int j = rem >> 7, k = rem & 127;
    float v = 0.f;
    if (g == 0) v = sp_root[k * 128 + j];
    else if (g < 8) {
      int r = g - 1;
#pragma unroll
      for (int b = 0; b < 4; ++b) v += sp_comp[r * 4 + b] * sp_basis[b * 16384 + k * 128 + j];
    } else if (g == 8) v = tp_root[k * 128 + j];
    else {
      int r = g - 9;
#pragma unroll
      for (int b = 0; b < 3; ++b) v += tp_comp[r * 3 + b] * tp_basis[b * 16384 + k * 128 + j];
    }
    WT[idx] = f2b(v);
  } else if (idx < 229376) {
    int rem = idx - 196608;
    int j = rem >> 8, k = rem & 255;
    FT[rem] = f2b(fw[k * 128 + j]);
  }
}

// ---------------- fused layer: gather-agg + MFMA + fuse + LN + residual ------
// 512 thr (8 waves), 32 dsts per block, grid = NN/32 = 4096.
__global__ __launch_bounds__(512) void k_layer(
    const u16* __restrict__ hin, u16* __restrict__ hout,
    const int* __restrict__ rowptr, const u32* __restrict__ colidx,
    const float* __restrict__ inv, const u16* __restrict__ WT,
    const u16* __restrict__ FT, const float* __restrict__ spb,
    const float* __restrict__ tpb, const float* __restrict__ fb,
    const float* __restrict__ lng, const float* __restrict__ lnb, int first) {
  __shared__ u16 AG[11][32][136];    // 95744 B: g0=h, g1..7 sp agg, g8..10 tp agg
  __shared__ u16 CT[32][264];        // 16896 B: cat(hs,ht) bf16
  __shared__ float FO[32][132];      // 16896 B: fuse out fp32
  const int tid = threadIdx.x;

  // phase 0: zero AG
  {
    u32* z = (u32*)AG;
#pragma unroll
    for (int i = 0; i < 47; ++i) {
      int p = tid + i * 512;
      if (p < 23936) z[p] = 0;
    }
  }
  __syncthreads();

  // phase 1: gather + per-relation mean into AG
  {
    int hw = tid >> 5, sub = tid & 31;
    for (int dd = 0; dd < 2; ++dd) {
      int dl = hw * 2 + dd;
      int d = blockIdx.x * 32 + dl;
      uint2 hv = *(const uint2*)&hin[(size_t)d * HH + sub * 4];
      *(uint2*)&AG[0][dl][sub * 4] = hv;
      int i = rowptr[d], end = rowptr[d + 1];
      float a0 = 0, a1 = 0, a2 = 0, a3 = 0;
      int pr = -1;
      u32 c0 = 0; uint2 v0 = {};
      if (i < end) {
        c0 = colidx[i];
        v0 = *(const uint2*)&hin[(size_t)(c0 >> 4) * HH + sub * 4];
        pr = (int)(c0 & 15u);
      }
      while (i < end) {
        u32 c1 = 0; uint2 v1 = v0;
        if (i + 1 < end) {
          c1 = colidx[i + 1];
          v1 = *(const uint2*)&hin[(size_t)(c1 >> 4) * HH + sub * 4];
        }
        int r = (int)(c0 & 15u);
        if (r != pr) {
          float sc = inv[pr * NN + d];
          u32 p0 = (u32)f2b(a0 * sc) | ((u32)f2b(a1 * sc) << 16);
          u32 p1 = (u32)f2b(a2 * sc) | ((u32)f2b(a3 * sc) << 16);
          *(uint2*)&AG[pr + 1][dl][sub * 4] = make_uint2(p0, p1);
          a0 = a1 = a2 = a3 = 0;
          pr = r;
        }
        a0 += b2f(v0.x & 0xFFFFu); a1 += b2f(v0.x >> 16);
        a2 += b2f(v0.y & 0xFFFFu); a3 += b2f(v0.y >> 16);
        c0 = c1; v0 = v1; ++i;
      }
      if (pr >= 0) {
        float sc = inv[pr * NN + d];
        u32 p0 = (u32)f2b(a0 * sc) | ((u32)f2b(a1 * sc) << 16);
        u32 p1 = (u32)f2b(a2 * sc) | ((u32)f2b(a3 * sc) << 16);
        *(uint2*)&AG[pr + 1][dl][sub * 4] = make_uint2(p0, p1);
      }
    }
  }
  __syncthreads();

  // phase 2: sp GEMM (waves 0-3) / tp GEMM (waves 4-7), M=32 N=32 each
  const int w = tid >> 6, lane = tid & 63;
  const int lr = lane & 15, lk = (lane >> 4) * 8;
  {
    f32x4 acc[2][2] = {};
    const bool issp = (w < 4);
    const int wn = (w & 3) * 32;
    if (issp) {
#pragma unroll
      for (int g = 0; g < 8; ++g)
#pragma unroll
        for (int kk = 0; kk < 4; ++kk) {
          int ko = kk * 32 + lk;
          bfx8 A0 = *(bfx8*)&AG[g][lr][ko];
          bfx8 A1 = *(bfx8*)&AG[g][16 + lr][ko];
          bfx8 B0 = *(const bfx8*)&WT[((size_t)g * 128 + wn + lr) * 128 + ko];
          bfx8 B1 = *(const bfx8*)&WT[((size_t)g * 128 + wn + 16 + lr) * 128 + ko];
          acc[0][0] = __builtin_amdgcn_mfma_f32_16x16x32_bf16(A0, B0, acc[0][0], 0, 0, 0);
          acc[0][1] = __builtin_amdgcn_mfma_f32_16x16x32_bf16(A0, B1, acc[0][1], 0, 0, 0);
          acc[1][0] = __builtin_amdgcn_mfma_f32_16x16x32_bf16(A1, B0, acc[1][0], 0, 0, 0);
          acc[1][1] = __builtin_amdgcn_mfma_f32_16x16x32_bf16(A1, B1, acc[1][1], 0, 0, 0);
        }
    } else {
#pragma unroll
      for (int gi = 0; gi < 4; ++gi) {
        const int agl[4] = {0, 8, 9, 10};
        const int bgl[4] = {8, 9, 10, 11};
        int ga = agl[gi], gb = bgl[gi];
#pragma unroll
        for (int kk = 0; kk < 4; ++kk) {
          int ko = kk * 32 + lk;
          bfx8 A0 = *(bfx8*)&AG[ga][lr][ko];
          bfx8 A1 = *(bfx8*)&AG[ga][16 + lr][ko];
          bfx8 B0 = *(const bfx8*)&WT[((size_t)gb * 128 + wn + lr) * 128 + ko];
          bfx8 B1 = *(const bfx8*)&WT[((size_t)gb * 128 + wn + 16 + lr) * 128 + ko];
          acc[0][0] = __builtin_amdgcn_mfma_f32_16x16x32_bf16(A0, B0, acc[0][0], 0, 0, 0);
          acc[0][1] = __builtin_amdgcn_mfma_f32_16x16x32_bf16(A0, B1, acc[0][1], 0, 0, 0);
          acc[1][0] = __builtin_amdgcn_mfma_f32_16x16x32_bf16(A1, B0, acc[1][0], 0, 0, 0);
          acc[1][1] = __builtin_amdgcn_mfma_f32_16x16x32_bf16(A1, B1, acc[1][1], 0, 0, 0);
        }
      }
    }
    const float* bias = issp ? spb : tpb;
    int cbase = issp ? 0 : 128;
    float bn0 = bias[wn + lr], bn1 = bias[wn + 16 + lr];
    int rb = (lane >> 4) * 4;
#pragma unroll
    for (int m = 0; m < 2; ++m)
#pragma unroll
      for (int n = 0; n < 2; ++n)
#pragma unroll
        for (int v = 0; v < 4; ++v) {
          int row = m * 16 + rb + v;
          int col = wn + n * 16 + lr;
          CT[row][cbase + col] = f2b(acc[m][n][v] + (n ? bn1 : bn0));
        }
  }
  __syncthreads();

  // phase 3: fuse GEMM, K=256, each wave owns 16 output cols
  {
    f32x4 fa[2] = {};
    int fc = w * 16;
#pragma unroll
    for (int g = 0; g < 8; ++g) {
      int ko = g * 32 + lk;
      bfx8 A0 = *(bfx8*)&CT[lr][ko];
      bfx8 A1 = *(bfx8*)&CT[16 + lr][ko];
      bfx8 B = *(const bfx8*)&FT[(size_t)(fc + lr) * 256 + ko];
      fa[0] = __builtin_amdgcn_mfma_f32_16x16x32_bf16(A0, B, fa[0], 0, 0, 0);
      fa[1] = __builtin_amdgcn_mfma_f32_16x16x32_bf16(A1, B, fa[1], 0, 0, 0);
    }
    int rb = (lane >> 4) * 4;
#pragma unroll
    for (int m = 0; m < 2; ++m)
#pragma unroll
      for (int v = 0; v < 4; ++v)
        FO[m * 16 + rb + v][fc + lr] = fa[m][v];
  }
  __syncthreads();

  // phase 4: +fb, LN, relu, residual, bf16 store
  {
    int hw = tid >> 5, sub = tid & 31;
    f32x4 fbv = *(const f32x4*)&fb[sub * 4];
    f32x4 gv = *(const f32x4*)&lng[sub * 4];
    f32x4 bv = *(const f32x4*)&lnb[sub * 4];
    for (int dd = 0; dd < 2; ++dd) {
      int dl = hw * 2 + dd;
      int d = blockIdx.x * 32 + dl;
      f32x4 vv = *(const f32x4*)&FO[dl][sub * 4];
      float v0 = vv.x + fbv.x, v1 = vv.y + fbv.y;
      float v2 = vv.z + fbv.z, v3 = vv.w + fbv.w;
      float s = v0 + v1 + v2 + v3;
#pragma unroll
      for (int dx = 1; dx < 32; dx <<= 1) s += __shfl_xor(s, dx);
      float mu = s * (1.f / 128.f);
      float e0 = v0 - mu, e1 = v1 - mu, e2 = v2 - mu, e3 = v3 - mu;
      float q = e0 * e0 + e1 * e1 + e2 * e2 + e3 * e3;
#pragma unroll
      for (int dx = 1; dx < 32; dx <<= 1) q += __shfl_xor(q, dx);
      float rstd = rsqrtf(q * (1.f / 128.f) + 1e-5f);
      float y0 = fmaxf(e0 * rstd * gv.x + bv.x, 0.f);
      float y1 = fmaxf(e1 * rstd * gv.y + bv.y, 0.f);
      float y2 = fmaxf(e2 * rstd * gv.z + bv.z, 0.f);
      float y3 = fmaxf(e3 * rstd * gv.w + bv.w, 0.f);
      size_t pp = (size_t)d * HH + sub * 4;
      if (!first) {
        uint2 hv = *(const uint2*)&hin[pp];
        y0 += b2f(hv.x & 0xFFFFu); y1 += b2f(hv.x >> 16);
        y2 += b2f(hv.y & 0xFFFFu); y3 += b2f(hv.y >> 16);
      }
      uint2 o;
      o.x = (u32)f2b(y0) | ((u32)f2b(y1) << 16);
      o.y = (u32)f2b(y2) | ((u32)f2b(y3) << 16);
      *(uint2*)&hout[pp] = o;
    }
  }
}

// ---------------- input projection: h = x @ w_in + b_in (bf16 out) -----------
__global__ __launch_bounds__(256) void k_input(const float* __restrict__ x,
                                               const float* __restrict__ w,
                                               const float* __restrict__ bias,
                                               u16* __restrict__ hb) {
  __shared__ float Ws[64 * 128];
  __shared__ float xr[4][4][64];
  for (int i = threadIdx.x * 4; i < 64 * 128; i += 1024)
    *(f32x4*)&Ws[i] = *(const f32x4*)&w[i];
  __syncthreads();
  int wid = threadIdx.x >> 6, lane = threadIdx.x & 63;
  int o0 = 2 * lane, o1 = o0 + 1;
  float b0 = bias[o0], b1 = bias[o1];
  for (int base = blockIdx.x * 16; base < NN; base += gridDim.x * 16) {
    int n0 = base + wid * 4;
#pragma unroll
    for (int nd = 0; nd < 4; ++nd)
      xr[wid][nd][lane] = x[(size_t)(n0 + nd) * 64 + lane];
    float acc[4][2] = {};
    for (int f = 0; f < 64; ++f) {
      float2 wv = *(const float2*)&Ws[f * 128 + o0];
#pragma unroll
      for (int nd = 0; nd < 4; ++nd) {
        float c = xr[wid][nd][f];
        acc[nd][0] = fmaf(c, wv.x, acc[nd][0]);
        acc[nd][1] = fmaf(c, wv.y, acc[nd][1]);
      }
    }
#pragma unroll
    for (int nd = 0; nd < 4; ++nd) {
      size_t pp = (size_t)(n0 + nd) * HH;
      float y0 = acc[nd][0] + b0, y1 = acc[nd][1] + b1;
      *(u32*)&hb[pp + o0] = (u32)f2b(y0) | ((u32)f2b(y1) << 16);
    }
  }
}

// ---------------- head: out = relu(h@W1+b1)@W2 + b2 --------------------------
__global__ __launch_bounds__(256) void k_head(const u16* __restrict__ hbuf,
                                              const float* __restrict__ w1,
                                              const float* __restrict__ b1,
                                              const float* __restrict__ w2,
                                              const float* __restrict__ b2,
                                              float* __restrict__ out) {
  __shared__ u16 W1s[128 * 128];
  __shared__ u16 W2s[128 * 32];
  __shared__ float hr[4][4][128];
  __shared__ float h1[4][4][128];
  for (int i = threadIdx.x * 4; i < 128 * 128; i += 1024) {
    f32x4 v = *(const f32x4*)&w1[i];
    uint2 pk;
    pk.x = (u32)f2b(v.x) | ((u32)f2b(v.y) << 16);
    pk.y = (u32)f2b(v.z) | ((u32)f2b(v.w) << 16);
    *(uint2*)&W1s[i] = pk;
  }
  for (int i = threadIdx.x * 4; i < 128 * 32; i += 1024) {
    f32x4 v = *(const f32x4*)&w2[i];
    uint2 pk;
    pk.x = (u32)f2b(v.x) | ((u32)f2b(v.y) << 16);
    pk.y = (u32)f2b(v.z) | ((u32)f2b(v.w) << 16);
    *(uint2*)&W2s[i] = pk;
  }
  __syncthreads();
  int wid = threadIdx.x >> 6, lane = threadIdx.x & 63;
  int o0 = 2 * lane, o1 = o0 + 1;
  float bb0 = b1[o0], bb1 = b1[o1];
  int o2 = lane & 31, half = lane >> 5;
  float b2v = b2[o2];
  for (int base = blockIdx.x * 16; base < NN; base += gridDim.x * 16) {
    int n0 = base + wid * 4;
#pragma unroll
    for (int nd = 0; nd < 4; ++nd) {
      size_t pp = (size_t)(n0 + nd) * HH;
      u32 hv = *(const u32*)&hbuf[pp + o0];
      hr[wid][nd][o0] = b2f(hv & 0xFFFFu);
      hr[wid][nd][o1] = b2f(hv >> 16);
    }
    float acc[4][2] = {};
    for (int f = 0; f < 128; ++f) {
      u32 w = *(const u32*)&W1s[f * 128 + o0];
      float wx = b2f(w & 0xFFFFu), wy = b2f(w >> 16);
#pragma unroll
      for (int nd = 0; nd < 4; ++nd) {
        float c = hr[wid][nd][f];
        acc[nd][0] = fmaf(c, wx, acc[nd][0]);
        acc[nd][1] = fmaf(c, wy, acc[nd][1]);
      }
    }
#pragma unroll
    for (int nd = 0; nd < 4; ++nd) {
      h1[wid][nd][o0] = fmaxf(acc[nd][0] + bb0, 0.f);
      h1[wid][nd][o1] = fmaxf(acc[nd][1] + bb1, 0.f);
    }
#pragma unroll
    for (int nd2 = 0; nd2 < 2; ++nd2) {
      int nd = half * 2 + nd2;
      float a = 0.f;
      for (int f = 0; f < 128; ++f)
        a = fmaf(h1[wid][nd][f], b2f(W2s[f * 32 + o2]), a);
      out[(size_t)(n0 + nd) * 32 + o2] = a + b2v;
    }
  }
}

extern "C" void kernel_launch(void* const* d_in, const int* in_sizes, int n_in,
                              void* d_out, int out_size, void* d_ws, size_t ws_size,
                              hipStream_t stream) {
  const float* x        = (const float*)d_in[0];
  const int*   ei       = (const int*)d_in[1];
  const int*   et       = (const int*)d_in[2];
  const float* w_in     = (const float*)d_in[3];
  const float* b_in     = (const float*)d_in[4];
  const float* sp_basis = (const float*)d_in[5];
  const float* sp_comp  = (const float*)d_in[6];
  const float* sp_root  = (const float*)d_in[7];
  const float* sp_bias  = (const float*)d_in[8];
  const float* tp_basis = (const float*)d_in[9];
  const float* tp_comp  = (const float*)d_in[10];
  const float* tp_root  = (const float*)d_in[11];
  const float* tp_bias  = (const float*)d_in[12];
  const float* fuse_w   = (const float*)d_in[13];
  const float* fuse_b   = (const float*)d_in[14];
  const float* ln_g     = (const float*)d_in[15];
  const float* ln_b     = (const float*)d_in[16];
  const float* hw1      = (const float*)d_in[17];
  const float* hb1      = (const float*)d_in[18];
  const float* hw2      = (const float*)d_in[19];
  const float* hb2      = (const float*)d_in[20];

  char* p = (char*)d_ws;
  size_t off = 0;
  auto carve = [&](size_t bytes) {
    void* q = p + off;
    off += (bytes + 255) & ~(size_t)255;
    return q;
  };
  u16* hbA    = (u16*)carve((size_t)NN * HH * 2);   // 32 MiB
  u16* hbB    = (u16*)carve((size_t)NN * HH * 2);   // 32 MiB
  int* cnt    = (int*)carve((size_t)10 * NN * 4);   //  5 MiB (becomes inv)
  int* deg    = (int*)carve((size_t)NN * 4);
  int* rowptr = (int*)carve((size_t)(NN + 1) * 4);
  int* cursor = (int*)carve((size_t)10 * NN * 4);   //  5 MiB
  u32* colidx = (u32*)carve((size_t)NE * 4);        //  6 MiB
  u16* WT     = (u16*)carve((size_t)12 * 16384 * 2);
  u16* FT     = (u16*)carve((size_t)128 * 256 * 2);
  (void)ws_size;  // total ~82 MiB, well under the ~256 MiB workspace

  hipMemsetAsync(cnt, 0, (size_t)10 * NN * 4, stream);
  hipMemsetAsync(deg, 0, (size_t)NN * 4, stream);
  k_count2<<<(NE + 255) / 256, 256, 0, stream>>>(et, ei + NE, cnt, deg);
  k_scan<<<1, 1024, 0, stream>>>(deg, rowptr);
  k_rpd<<<(NN + 255) / 256, 256, 0, stream>>>(cnt, rowptr, cursor);
  k_inv<<<(10 * NN + 255) / 256, 256, 0, stream>>>(cnt);
  k_fill<<<(NE + 255) / 256, 256, 0, stream>>>(ei, ei + NE, et, cursor, colidx);
  k_input<<<2048, 256, 0, stream>>>(x, w_in, b_in, hbA);

  for (int l = 0; l < 3; ++l) {
    k_prep<<<896, 256, 0, stream>>>(
        sp_root + (size_t)l * 16384, tp_root + (size_t)l * 16384,
        sp_basis + (size_t)l * 4 * 16384, sp_comp + (size_t)l * 28,
        tp_basis + (size_t)l * 3 * 16384, tp_comp + (size_t)l * 9,
        fuse_w + (size_t)l * 32768, WT, FT);
    const u16* hin = (l & 1) ? hbB : hbA;
    u16* hout = (l & 1) ? hbA : hbB;
    k_layer<<<NN / 32, 512, 0, stream>>>(
        hin, hout, rowptr, colidx, (const float*)cnt, WT, FT,
        sp_bias + l * 128, tp_bias + l * 128, fuse_b + l * 128,
        ln_g + l * 128, ln_b + l * 128, l == 0);
  }
  k_head<<<2048, 256, 0, stream>>>(hbB, hw1, hb1, hw2, hb2, (float*)d_out);
}